// Round 1
// baseline (93.160 us; speedup 1.0000x reference)
//
#include <hip/hip_runtime.h>
#include <math.h>

// SetCriterion (YOLOv5 loss) on MI355X.
// Heads: H = {80,40,20}, N = {4000,2000,1000}, M = 16*3*H*H.
// Output: [loss*16, lbox, lobj, lcls, loss] (float32, 5 elems).
//
// BCE identity: mean(t*sp(-x)+(1-t)*sp(x)) = mean(sp(x)) - mean(t*x)
// => never materialize tobj / one-hot cls.

#define BLK 256
#define GA  128   // blocks per head for obj-softplus reduction
#define GBX 16    // blocks per head for per-target kernel (covers N0=4000)

__device__ inline float softplusf(float x) {
    // logaddexp(x, 0) = max(x,0) + log1p(exp(-|x|))
    return fmaxf(x, 0.0f) + log1pf(expf(-fabsf(x)));
}

__device__ inline float sigmoidf_(float x) {
    return 1.0f / (1.0f + expf(-x));
}

__device__ inline double block_reduce(double v, double* sm) {
    sm[threadIdx.x] = v;
    __syncthreads();
    for (int s = BLK / 2; s > 0; s >>= 1) {
        if (threadIdx.x < (unsigned)s) sm[threadIdx.x] += sm[threadIdx.x + s];
        __syncthreads();
    }
    return sm[0];
}

// ---------------- Kernel A: sum of softplus over obj channel (ch 4) ----------
__global__ void obj_sp_kernel(const float* __restrict__ p0,
                              const float* __restrict__ p1,
                              const float* __restrict__ p2,
                              int M0, int M1, int M2,
                              double* __restrict__ out /* [3][gridDim.x] */) {
    const int h = blockIdx.y;
    const float* p = (h == 0) ? p0 : ((h == 1) ? p1 : p2);
    const int M = (h == 0) ? M0 : ((h == 1) ? M1 : M2);
    double acc = 0.0;
    const int stride = gridDim.x * blockDim.x;
    for (int i = blockIdx.x * blockDim.x + threadIdx.x; i < M; i += stride) {
        float x = p[(size_t)i * 85 + 4];
        acc += (double)softplusf(x);
    }
    __shared__ double sm[BLK];
    double tot = block_reduce(acc, sm);
    if (threadIdx.x == 0) out[h * gridDim.x + blockIdx.x] = tot;
}

// ---------------- Kernel B1: last-duplicate-wins via atomicMax ---------------
__global__ void winner_kernel(const int* __restrict__ i0,
                              const int* __restrict__ i1,
                              const int* __restrict__ i2,
                              int N0, int N1, int N2,
                              int H0, int H1, int H2,
                              int off0, int off1, int off2,
                              int* __restrict__ winner) {
    const int h = blockIdx.y;
    const int* idx = (h == 0) ? i0 : ((h == 1) ? i1 : i2);
    const int N = (h == 0) ? N0 : ((h == 1) ? N1 : N2);
    const int H = (h == 0) ? H0 : ((h == 1) ? H1 : H2);
    const int off = (h == 0) ? off0 : ((h == 1) ? off1 : off2);
    const int n = blockIdx.x * blockDim.x + threadIdx.x;
    if (n >= N) return;
    const int b = idx[n], a = idx[N + n], gj = idx[2 * N + n], gi = idx[3 * N + n];
    const int c = ((b * 3 + a) * H + gj) * H + gi;
    atomicMax(&winner[off + c], n);
}

// ---------------- Kernel B2: per-target lbox / lcls / obj-subtract -----------
__global__ void target_kernel(const float* __restrict__ p0, const float* __restrict__ p1, const float* __restrict__ p2,
                              const int* __restrict__ i0, const int* __restrict__ i1, const int* __restrict__ i2,
                              const float* __restrict__ tb0, const float* __restrict__ tb1, const float* __restrict__ tb2,
                              const float* __restrict__ an0, const float* __restrict__ an1, const float* __restrict__ an2,
                              const int* __restrict__ lb0, const int* __restrict__ lb1, const int* __restrict__ lb2,
                              int N0, int N1, int N2,
                              int H0, int H1, int H2,
                              int off0, int off1, int off2,
                              const int* __restrict__ winner,
                              double* __restrict__ outLbox,
                              double* __restrict__ outClsSp,
                              double* __restrict__ outClsLab,
                              double* __restrict__ outObjSub) {
    const int h = blockIdx.y;
    const float* pi  = (h == 0) ? p0  : ((h == 1) ? p1  : p2);
    const int*   idx = (h == 0) ? i0  : ((h == 1) ? i1  : i2);
    const float* tbx = (h == 0) ? tb0 : ((h == 1) ? tb1 : tb2);
    const float* anc = (h == 0) ? an0 : ((h == 1) ? an1 : an2);
    const int*   lab = (h == 0) ? lb0 : ((h == 1) ? lb1 : lb2);
    const int N   = (h == 0) ? N0 : ((h == 1) ? N1 : N2);
    const int H   = (h == 0) ? H0 : ((h == 1) ? H1 : H2);
    const int off = (h == 0) ? off0 : ((h == 1) ? off1 : off2);

    const int n = blockIdx.x * blockDim.x + threadIdx.x;

    double lbox = 0.0, clssp = 0.0, clslab = 0.0, objsub = 0.0;

    if (n < N) {
        const int b = idx[n], a = idx[N + n], gj = idx[2 * N + n], gi = idx[3 * N + n];
        const int c = ((b * 3 + a) * H + gj) * H + gi;
        const size_t base = (size_t)c * 85;

        const float lx = pi[base + 0], ly = pi[base + 1];
        const float lw = pi[base + 2], lh = pi[base + 3];
        const float xo = pi[base + 4];

        // pred box
        const float px = sigmoidf_(lx) * 2.0f - 0.5f;
        const float py = sigmoidf_(ly) * 2.0f - 0.5f;
        float sw = sigmoidf_(lw) * 2.0f;
        float sh = sigmoidf_(lh) * 2.0f;
        const float pw = sw * sw * anc[(size_t)n * 2 + 0];
        const float ph = sh * sh * anc[(size_t)n * 2 + 1];

        const float tx = tbx[(size_t)n * 4 + 0], ty = tbx[(size_t)n * 4 + 1];
        const float tw = tbx[(size_t)n * 4 + 2], th = tbx[(size_t)n * 4 + 3];

        // CIoU (box1 = pred, box2 = target)
        const float b1x1 = px - pw * 0.5f, b1x2 = px + pw * 0.5f;
        const float b1y1 = py - ph * 0.5f, b1y2 = py + ph * 0.5f;
        const float b2x1 = tx - tw * 0.5f, b2x2 = tx + tw * 0.5f;
        const float b2y1 = ty - th * 0.5f, b2y2 = ty + th * 0.5f;

        const float iw = fmaxf(fminf(b1x2, b2x2) - fmaxf(b1x1, b2x1), 0.0f);
        const float ih = fmaxf(fminf(b1y2, b2y2) - fmaxf(b1y1, b2y1), 0.0f);
        const float inter = iw * ih;
        const float uni = pw * ph + tw * th - inter + 1e-7f;
        const float iou = inter / uni;

        const float cw = fmaxf(b1x2, b2x2) - fminf(b1x1, b2x1);
        const float ch = fmaxf(b1y2, b2y2) - fminf(b1y1, b2y1);
        const float c2 = cw * cw + ch * ch + 1e-7f;
        const float dx = b2x1 + b2x2 - b1x1 - b1x2;
        const float dy = b2y1 + b2y2 - b1y1 - b1y2;
        const float rho2 = (dx * dx + dy * dy) * 0.25f;
        const float dat = atanf(tw / (th + 1e-7f)) - atanf(pw / (ph + 1e-7f));
        const float v = 0.4052847345693511f * dat * dat;   // 4/pi^2
        const float alpha = v / (v - iou + (1.0f + 1e-7f));
        const float ciou = iou - (rho2 / c2 + v * alpha);

        lbox = 1.0 - (double)ciou;

        // classification: sum softplus over 80 logits, and label logit
        double sp = 0.0;
        for (int cc = 0; cc < 80; ++cc) {
            sp += (double)softplusf(pi[base + 5 + cc]);
        }
        clssp = sp;
        clslab = (double)pi[base + 5 + lab[n]];

        // obj subtract term: only the winning duplicate contributes
        if (winner[off + c] == n) {
            const float tobj = fmaxf(ciou, 0.0f);
            objsub = (double)tobj * (double)xo;
        }
    }

    __shared__ double sm[BLK];
    double r;
    r = block_reduce(lbox, sm);
    if (threadIdx.x == 0) outLbox[h * gridDim.x + blockIdx.x] = r;
    __syncthreads();
    r = block_reduce(clssp, sm);
    if (threadIdx.x == 0) outClsSp[h * gridDim.x + blockIdx.x] = r;
    __syncthreads();
    r = block_reduce(clslab, sm);
    if (threadIdx.x == 0) outClsLab[h * gridDim.x + blockIdx.x] = r;
    __syncthreads();
    r = block_reduce(objsub, sm);
    if (threadIdx.x == 0) outObjSub[h * gridDim.x + blockIdx.x] = r;
}

// ---------------- Kernel C: final combine ------------------------------------
__global__ void final_kernel(const double* __restrict__ objsp, int ga,
                             const double* __restrict__ lboxp,
                             const double* __restrict__ clssp,
                             const double* __restrict__ clslab,
                             const double* __restrict__ objsub, int gb,
                             int M0, int M1, int M2,
                             int N0, int N1, int N2,
                             float* __restrict__ out) {
    if (blockIdx.x != 0 || threadIdx.x != 0) return;
    const double Ms[3] = {(double)M0, (double)M1, (double)M2};
    const double Ns[3] = {(double)N0, (double)N1, (double)N2};
    const double bal[3] = {4.0, 1.0, 0.4};

    double lbox = 0.0, lobj = 0.0, lcls = 0.0;
    for (int h = 0; h < 3; ++h) {
        double sp = 0.0;
        for (int i = 0; i < ga; ++i) sp += objsp[h * ga + i];
        double lb = 0.0, cs = 0.0, cl = 0.0, os = 0.0;
        for (int i = 0; i < gb; ++i) {
            lb += lboxp[h * gb + i];
            cs += clssp[h * gb + i];
            cl += clslab[h * gb + i];
            os += objsub[h * gb + i];
        }
        lbox += lb / Ns[h];
        lobj += bal[h] * (sp - os) / Ms[h];
        lcls += (cs - cl) / (Ns[h] * 80.0);
    }
    lbox *= 0.05;   // _BOX_W
    lcls *= 0.5;    // _CLS_W
    // _OBJ_W = 1.0
    const double loss = lbox + lobj + lcls;
    out[0] = (float)(loss * 16.0);  // bs = 16
    out[1] = (float)lbox;
    out[2] = (float)lobj;
    out[3] = (float)lcls;
    out[4] = (float)loss;
}

extern "C" void kernel_launch(void* const* d_in, const int* in_sizes, int n_in,
                              void* d_out, int out_size, void* d_ws, size_t ws_size,
                              hipStream_t stream) {
    const int H0 = 80, H1 = 40, H2 = 20;
    const int M0 = 16 * 3 * H0 * H0;  // 307200
    const int M1 = 16 * 3 * H1 * H1;  // 76800
    const int M2 = 16 * 3 * H2 * H2;  // 19200

    // Input index mapping: prefer setup_inputs() dict order
    // (pi0, idx0, tbox0, anchors0, labels0, pi1, ...). Detect defensively:
    // in dict order in_sizes[1] == 4*N0 (small); in signature order it is pi1.
    int ip[3], ii[3], it[3], ia[3], il[3];
    if (in_sizes[1] < 100000) {
        for (int h = 0; h < 3; ++h) {
            ip[h] = 5 * h; ii[h] = 5 * h + 1; it[h] = 5 * h + 2;
            ia[h] = 5 * h + 3; il[h] = 5 * h + 4;
        }
    } else {
        for (int h = 0; h < 3; ++h) {
            ip[h] = h; ii[h] = 3 + h; it[h] = 6 + h;
            ia[h] = 9 + h; il[h] = 12 + h;
        }
    }
    const float* p0 = (const float*)d_in[ip[0]];
    const float* p1 = (const float*)d_in[ip[1]];
    const float* p2 = (const float*)d_in[ip[2]];
    const int* i0 = (const int*)d_in[ii[0]];
    const int* i1 = (const int*)d_in[ii[1]];
    const int* i2 = (const int*)d_in[ii[2]];
    const float* tb0 = (const float*)d_in[it[0]];
    const float* tb1 = (const float*)d_in[it[1]];
    const float* tb2 = (const float*)d_in[it[2]];
    const float* an0 = (const float*)d_in[ia[0]];
    const float* an1 = (const float*)d_in[ia[1]];
    const float* an2 = (const float*)d_in[ia[2]];
    const int* lb0 = (const int*)d_in[il[0]];
    const int* lb1 = (const int*)d_in[il[1]];
    const int* lb2 = (const int*)d_in[il[2]];

    const int N0 = in_sizes[ii[0]] / 4;  // 4000
    const int N1 = in_sizes[ii[1]] / 4;  // 2000
    const int N2 = in_sizes[ii[2]] / 4;  // 1000

    // Workspace layout
    const int totalM = M0 + M1 + M2;              // 403200 ints
    int* winner = (int*)d_ws;
    char* dptr = (char*)d_ws + (((size_t)totalM * 4 + 255) / 256) * 256;
    double* objsp  = (double*)dptr;               // 3*GA
    double* lboxp  = objsp + 3 * GA;              // 3*GBX
    double* clsspP = lboxp + 3 * GBX;
    double* clslabP = clsspP + 3 * GBX;
    double* objsubP = clslabP + 3 * GBX;

    const int off0 = 0, off1 = M0, off2 = M0 + M1;

    hipMemsetAsync(winner, 0xFF, (size_t)totalM * sizeof(int), stream);

    obj_sp_kernel<<<dim3(GA, 3), BLK, 0, stream>>>(p0, p1, p2, M0, M1, M2, objsp);

    const int gbx = (N0 + BLK - 1) / BLK;  // 16, covers all heads
    winner_kernel<<<dim3(gbx, 3), BLK, 0, stream>>>(i0, i1, i2, N0, N1, N2,
                                                    H0, H1, H2, off0, off1, off2, winner);

    target_kernel<<<dim3(gbx, 3), BLK, 0, stream>>>(
        p0, p1, p2, i0, i1, i2, tb0, tb1, tb2, an0, an1, an2, lb0, lb1, lb2,
        N0, N1, N2, H0, H1, H2, off0, off1, off2, winner,
        lboxp, clsspP, clslabP, objsubP);

    final_kernel<<<1, 64, 0, stream>>>(objsp, GA, lboxp, clsspP, clslabP, objsubP, gbx,
                                       M0, M1, M2, N0, N1, N2, (float*)d_out);
}

// Round 2
// 90.365 us; speedup vs baseline: 1.0309x; 1.0309x over previous
//
#include <hip/hip_runtime.h>
#include <math.h>

// SetCriterion (YOLOv5 loss) on MI355X.
// Heads: H = {80,40,20}, N = {4000,2000,1000}, M = 16*3*H*H.
// Output: [loss*16, lbox, lobj, lcls, loss] (float32, 5 elems).
//
// BCE identity: mean(t*sp(-x)+(1-t)*sp(x)) = mean(sp(x)) - mean(t*x)
// => never materialize tobj / one-hot cls.
//
// R2: killed the 1.6MB hipMemsetAsync (rocclr fill kernel was 60us of 93us,
// latency-bound tiny grid). winner[] only matters at touched cells, so we
// scatter-clear just the ~7000 touched cells, fused into kernel A's launch.

#define BLK 256
#define GA  128   // blocks per head for obj-softplus reduction

__device__ inline float softplusf(float x) {
    // logaddexp(x, 0) = max(x,0) + log1p(exp(-|x|))
    return fmaxf(x, 0.0f) + log1pf(expf(-fabsf(x)));
}

__device__ inline float sigmoidf_(float x) {
    return 1.0f / (1.0f + expf(-x));
}

__device__ inline double block_reduce(double v, double* sm) {
    sm[threadIdx.x] = v;
    __syncthreads();
    for (int s = BLK / 2; s > 0; s >>= 1) {
        if (threadIdx.x < (unsigned)s) sm[threadIdx.x] += sm[threadIdx.x + s];
        __syncthreads();
    }
    return sm[0];
}

__device__ inline int cell_of(const int* __restrict__ idx, int N, int H, int n) {
    const int b = idx[n], a = idx[N + n], gj = idx[2 * N + n], gi = idx[3 * N + n];
    return ((b * 3 + a) * H + gj) * H + gi;
}

// -------- Kernel A: obj-channel softplus sums (y=0..2) + winner clear (y=3) --
__global__ void obj_sp_clear_kernel(const float* __restrict__ p0,
                                    const float* __restrict__ p1,
                                    const float* __restrict__ p2,
                                    const int* __restrict__ i0,
                                    const int* __restrict__ i1,
                                    const int* __restrict__ i2,
                                    int M0, int M1, int M2,
                                    int N0, int N1, int N2,
                                    int H0, int H1, int H2,
                                    int off0, int off1, int off2,
                                    int* __restrict__ winner,
                                    double* __restrict__ out /* [3][GA] */) {
    const int h = blockIdx.y;
    if (h == 3) {
        // scatter-clear: winner[cell(n)] = -1 for every target of every head.
        // All stores write the same value -> race-free and deterministic.
        const int t = blockIdx.x * blockDim.x + threadIdx.x;
        const int Ntot = N0 + N1 + N2;
        if (t >= Ntot) return;
        if (t < N0) {
            winner[off0 + cell_of(i0, N0, H0, t)] = -1;
        } else if (t < N0 + N1) {
            const int n = t - N0;
            winner[off1 + cell_of(i1, N1, H1, n)] = -1;
        } else {
            const int n = t - N0 - N1;
            winner[off2 + cell_of(i2, N2, H2, n)] = -1;
        }
        return;
    }
    const float* p = (h == 0) ? p0 : ((h == 1) ? p1 : p2);
    const int M = (h == 0) ? M0 : ((h == 1) ? M1 : M2);
    double acc = 0.0;
    const int stride = gridDim.x * blockDim.x;
    for (int i = blockIdx.x * blockDim.x + threadIdx.x; i < M; i += stride) {
        float x = p[(size_t)i * 85 + 4];
        acc += (double)softplusf(x);
    }
    __shared__ double sm[BLK];
    double tot = block_reduce(acc, sm);
    if (threadIdx.x == 0) out[h * gridDim.x + blockIdx.x] = tot;
}

// ---------------- Kernel B1: last-duplicate-wins via atomicMax ---------------
__global__ void winner_kernel(const int* __restrict__ i0,
                              const int* __restrict__ i1,
                              const int* __restrict__ i2,
                              int N0, int N1, int N2,
                              int H0, int H1, int H2,
                              int off0, int off1, int off2,
                              int* __restrict__ winner) {
    const int h = blockIdx.y;
    const int* idx = (h == 0) ? i0 : ((h == 1) ? i1 : i2);
    const int N = (h == 0) ? N0 : ((h == 1) ? N1 : N2);
    const int H = (h == 0) ? H0 : ((h == 1) ? H1 : H2);
    const int off = (h == 0) ? off0 : ((h == 1) ? off1 : off2);
    const int n = blockIdx.x * blockDim.x + threadIdx.x;
    if (n >= N) return;
    atomicMax(&winner[off + cell_of(idx, N, H, n)], n);
}

// ---------------- Kernel B2: per-target lbox / lcls / obj-subtract -----------
__global__ void target_kernel(const float* __restrict__ p0, const float* __restrict__ p1, const float* __restrict__ p2,
                              const int* __restrict__ i0, const int* __restrict__ i1, const int* __restrict__ i2,
                              const float* __restrict__ tb0, const float* __restrict__ tb1, const float* __restrict__ tb2,
                              const float* __restrict__ an0, const float* __restrict__ an1, const float* __restrict__ an2,
                              const int* __restrict__ lb0, const int* __restrict__ lb1, const int* __restrict__ lb2,
                              int N0, int N1, int N2,
                              int H0, int H1, int H2,
                              int off0, int off1, int off2,
                              const int* __restrict__ winner,
                              double* __restrict__ outLbox,
                              double* __restrict__ outClsSp,
                              double* __restrict__ outClsLab,
                              double* __restrict__ outObjSub) {
    const int h = blockIdx.y;
    const float* pi  = (h == 0) ? p0  : ((h == 1) ? p1  : p2);
    const int*   idx = (h == 0) ? i0  : ((h == 1) ? i1  : i2);
    const float* tbx = (h == 0) ? tb0 : ((h == 1) ? tb1 : tb2);
    const float* anc = (h == 0) ? an0 : ((h == 1) ? an1 : an2);
    const int*   lab = (h == 0) ? lb0 : ((h == 1) ? lb1 : lb2);
    const int N   = (h == 0) ? N0 : ((h == 1) ? N1 : N2);
    const int H   = (h == 0) ? H0 : ((h == 1) ? H1 : H2);
    const int off = (h == 0) ? off0 : ((h == 1) ? off1 : off2);

    const int n = blockIdx.x * blockDim.x + threadIdx.x;

    double lbox = 0.0, clssp = 0.0, clslab = 0.0, objsub = 0.0;

    if (n < N) {
        const int c = cell_of(idx, N, H, n);
        const size_t base = (size_t)c * 85;

        const float lx = pi[base + 0], ly = pi[base + 1];
        const float lw = pi[base + 2], lh = pi[base + 3];
        const float xo = pi[base + 4];

        // pred box
        const float px = sigmoidf_(lx) * 2.0f - 0.5f;
        const float py = sigmoidf_(ly) * 2.0f - 0.5f;
        float sw = sigmoidf_(lw) * 2.0f;
        float sh = sigmoidf_(lh) * 2.0f;
        const float pw = sw * sw * anc[(size_t)n * 2 + 0];
        const float ph = sh * sh * anc[(size_t)n * 2 + 1];

        const float tx = tbx[(size_t)n * 4 + 0], ty = tbx[(size_t)n * 4 + 1];
        const float tw = tbx[(size_t)n * 4 + 2], th = tbx[(size_t)n * 4 + 3];

        // CIoU (box1 = pred, box2 = target)
        const float b1x1 = px - pw * 0.5f, b1x2 = px + pw * 0.5f;
        const float b1y1 = py - ph * 0.5f, b1y2 = py + ph * 0.5f;
        const float b2x1 = tx - tw * 0.5f, b2x2 = tx + tw * 0.5f;
        const float b2y1 = ty - th * 0.5f, b2y2 = ty + th * 0.5f;

        const float iw = fmaxf(fminf(b1x2, b2x2) - fmaxf(b1x1, b2x1), 0.0f);
        const float ih = fmaxf(fminf(b1y2, b2y2) - fmaxf(b1y1, b2y1), 0.0f);
        const float inter = iw * ih;
        const float uni = pw * ph + tw * th - inter + 1e-7f;
        const float iou = inter / uni;

        const float cw = fmaxf(b1x2, b2x2) - fminf(b1x1, b2x1);
        const float ch = fmaxf(b1y2, b2y2) - fminf(b1y1, b2y1);
        const float c2 = cw * cw + ch * ch + 1e-7f;
        const float dx = b2x1 + b2x2 - b1x1 - b1x2;
        const float dy = b2y1 + b2y2 - b1y1 - b1y2;
        const float rho2 = (dx * dx + dy * dy) * 0.25f;
        const float dat = atanf(tw / (th + 1e-7f)) - atanf(pw / (ph + 1e-7f));
        const float v = 0.4052847345693511f * dat * dat;   // 4/pi^2
        const float alpha = v / (v - iou + (1.0f + 1e-7f));
        const float ciou = iou - (rho2 / c2 + v * alpha);

        lbox = 1.0 - (double)ciou;

        // classification: sum softplus over 80 logits, and label logit
        double sp = 0.0;
        for (int cc = 0; cc < 80; ++cc) {
            sp += (double)softplusf(pi[base + 5 + cc]);
        }
        clssp = sp;
        clslab = (double)pi[base + 5 + lab[n]];

        // obj subtract term: only the winning duplicate contributes
        if (winner[off + c] == n) {
            const float tobj = fmaxf(ciou, 0.0f);
            objsub = (double)tobj * (double)xo;
        }
    }

    __shared__ double sm[BLK];
    double r;
    r = block_reduce(lbox, sm);
    if (threadIdx.x == 0) outLbox[h * gridDim.x + blockIdx.x] = r;
    __syncthreads();
    r = block_reduce(clssp, sm);
    if (threadIdx.x == 0) outClsSp[h * gridDim.x + blockIdx.x] = r;
    __syncthreads();
    r = block_reduce(clslab, sm);
    if (threadIdx.x == 0) outClsLab[h * gridDim.x + blockIdx.x] = r;
    __syncthreads();
    r = block_reduce(objsub, sm);
    if (threadIdx.x == 0) outObjSub[h * gridDim.x + blockIdx.x] = r;
}

// ---------------- Kernel C: final combine ------------------------------------
__global__ void final_kernel(const double* __restrict__ objsp, int ga,
                             const double* __restrict__ lboxp,
                             const double* __restrict__ clssp,
                             const double* __restrict__ clslab,
                             const double* __restrict__ objsub, int gb,
                             int M0, int M1, int M2,
                             int N0, int N1, int N2,
                             float* __restrict__ out) {
    if (blockIdx.x != 0 || threadIdx.x != 0) return;
    const double Ms[3] = {(double)M0, (double)M1, (double)M2};
    const double Ns[3] = {(double)N0, (double)N1, (double)N2};
    const double bal[3] = {4.0, 1.0, 0.4};

    double lbox = 0.0, lobj = 0.0, lcls = 0.0;
    for (int h = 0; h < 3; ++h) {
        double sp = 0.0;
        for (int i = 0; i < ga; ++i) sp += objsp[h * ga + i];
        double lb = 0.0, cs = 0.0, cl = 0.0, os = 0.0;
        for (int i = 0; i < gb; ++i) {
            lb += lboxp[h * gb + i];
            cs += clssp[h * gb + i];
            cl += clslab[h * gb + i];
            os += objsub[h * gb + i];
        }
        lbox += lb / Ns[h];
        lobj += bal[h] * (sp - os) / Ms[h];
        lcls += (cs - cl) / (Ns[h] * 80.0);
    }
    lbox *= 0.05;   // _BOX_W
    lcls *= 0.5;    // _CLS_W
    // _OBJ_W = 1.0
    const double loss = lbox + lobj + lcls;
    out[0] = (float)(loss * 16.0);  // bs = 16
    out[1] = (float)lbox;
    out[2] = (float)lobj;
    out[3] = (float)lcls;
    out[4] = (float)loss;
}

extern "C" void kernel_launch(void* const* d_in, const int* in_sizes, int n_in,
                              void* d_out, int out_size, void* d_ws, size_t ws_size,
                              hipStream_t stream) {
    const int H0 = 80, H1 = 40, H2 = 20;
    const int M0 = 16 * 3 * H0 * H0;  // 307200
    const int M1 = 16 * 3 * H1 * H1;  // 76800
    const int M2 = 16 * 3 * H2 * H2;  // 19200

    // Input index mapping: prefer setup_inputs() dict order
    // (pi0, idx0, tbox0, anchors0, labels0, pi1, ...). Detect defensively.
    int ip[3], ii[3], it[3], ia[3], il[3];
    if (in_sizes[1] < 100000) {
        for (int h = 0; h < 3; ++h) {
            ip[h] = 5 * h; ii[h] = 5 * h + 1; it[h] = 5 * h + 2;
            ia[h] = 5 * h + 3; il[h] = 5 * h + 4;
        }
    } else {
        for (int h = 0; h < 3; ++h) {
            ip[h] = h; ii[h] = 3 + h; it[h] = 6 + h;
            ia[h] = 9 + h; il[h] = 12 + h;
        }
    }
    const float* p0 = (const float*)d_in[ip[0]];
    const float* p1 = (const float*)d_in[ip[1]];
    const float* p2 = (const float*)d_in[ip[2]];
    const int* i0 = (const int*)d_in[ii[0]];
    const int* i1 = (const int*)d_in[ii[1]];
    const int* i2 = (const int*)d_in[ii[2]];
    const float* tb0 = (const float*)d_in[it[0]];
    const float* tb1 = (const float*)d_in[it[1]];
    const float* tb2 = (const float*)d_in[it[2]];
    const float* an0 = (const float*)d_in[ia[0]];
    const float* an1 = (const float*)d_in[ia[1]];
    const float* an2 = (const float*)d_in[ia[2]];
    const int* lb0 = (const int*)d_in[il[0]];
    const int* lb1 = (const int*)d_in[il[1]];
    const int* lb2 = (const int*)d_in[il[2]];

    const int N0 = in_sizes[ii[0]] / 4;  // 4000
    const int N1 = in_sizes[ii[1]] / 4;  // 2000
    const int N2 = in_sizes[ii[2]] / 4;  // 1000

    // Workspace layout
    const int totalM = M0 + M1 + M2;              // 403200 ints
    int* winner = (int*)d_ws;
    char* dptr = (char*)d_ws + (((size_t)totalM * 4 + 255) / 256) * 256;
    double* objsp  = (double*)dptr;               // 3*GA
    double* lboxp  = objsp + 3 * GA;              // 3*gbx
    double* clsspP = lboxp + 3 * 16;
    double* clslabP = clsspP + 3 * 16;
    double* objsubP = clslabP + 3 * 16;

    const int off0 = 0, off1 = M0, off2 = M0 + M1;

    // Kernel A: y=0..2 obj softplus partials, y=3 scatter-clear of winner cells
    obj_sp_clear_kernel<<<dim3(GA, 4), BLK, 0, stream>>>(
        p0, p1, p2, i0, i1, i2, M0, M1, M2, N0, N1, N2,
        H0, H1, H2, off0, off1, off2, winner, objsp);

    const int gbx = (N0 + BLK - 1) / BLK;  // 16, covers all heads
    winner_kernel<<<dim3(gbx, 3), BLK, 0, stream>>>(i0, i1, i2, N0, N1, N2,
                                                    H0, H1, H2, off0, off1, off2, winner);

    target_kernel<<<dim3(gbx, 3), BLK, 0, stream>>>(
        p0, p1, p2, i0, i1, i2, tb0, tb1, tb2, an0, an1, an2, lb0, lb1, lb2,
        N0, N1, N2, H0, H1, H2, off0, off1, off2, winner,
        lboxp, clsspP, clslabP, objsubP);

    final_kernel<<<1, 64, 0, stream>>>(objsp, GA, lboxp, clsspP, clslabP, objsubP, gbx,
                                       M0, M1, M2, N0, N1, N2, (float*)d_out);
}

// Round 3
// 79.625 us; speedup vs baseline: 1.1700x; 1.1349x over previous
//
#include <hip/hip_runtime.h>
#include <math.h>

// SetCriterion (YOLOv5 loss) on MI355X.
// Heads: H = {80,40,20}, N = {4000,2000,1000}, M = 16*3*H*H.
// Output: [loss*16, lbox, lobj, lcls, loss] (float32, 5 elems).
//
// BCE identity: mean(t*sp(-x)+(1-t)*sp(x)) = mean(sp(x)) - mean(t*x)
// => never materialize tobj / one-hot cls.
//
// R3: 2 launches total. Kernel1: y=0..2 obj-softplus partials (strided
// channel-4 reads, the only big traffic), y=3 per-target blocks that resolve
// last-duplicate-wins via a per-block LDS hash (atomicCAS key + atomicMax val)
// -- no global winner array, no clear pass, no cross-launch ordering.
// Kernel2: tiny deterministic combine. The remaining ~62us/replay is the
// harness's own 408MB d_ws poison fill (fillBufferAligned @6.8TB/s), outside
// our control.

#define BLK  256
#define GA   128    // blocks per head for obj-softplus reduction
#define HASH 6144   // per-block LDS hash slots (max N=4000 -> load 0.65)

__device__ inline float softplusf(float x) {
    return fmaxf(x, 0.0f) + log1pf(expf(-fabsf(x)));   // logaddexp(x,0)
}

__device__ inline float sigmoidf_(float x) {
    return 1.0f / (1.0f + expf(-x));
}

__device__ inline int cell_of(const int* __restrict__ idx, int N, int H, int n) {
    const int b = idx[n], a = idx[N + n], gj = idx[2 * N + n], gi = idx[3 * N + n];
    return ((b * 3 + a) * H + gj) * H + gi;
}

__device__ inline int hash_insert(int* hkey, int cell) {
    int slot = cell % HASH;
    while (true) {
        int prev = atomicCAS(&hkey[slot], -1, cell);
        if (prev == -1 || prev == cell) return slot;
        slot = (slot + 1 == HASH) ? 0 : slot + 1;
    }
}

__device__ inline int hash_lookup(const int* hkey, int cell) {
    int slot = cell % HASH;
    while (true) {
        if (hkey[slot] == cell) return slot;
        slot = (slot + 1 == HASH) ? 0 : slot + 1;
    }
}

// ---------------- Kernel 1: everything except the final combine --------------
__global__ void __launch_bounds__(BLK)
main_kernel(const float* __restrict__ p0, const float* __restrict__ p1, const float* __restrict__ p2,
            const int* __restrict__ i0, const int* __restrict__ i1, const int* __restrict__ i2,
            const float* __restrict__ tb0, const float* __restrict__ tb1, const float* __restrict__ tb2,
            const float* __restrict__ an0, const float* __restrict__ an1, const float* __restrict__ an2,
            const int* __restrict__ lb0, const int* __restrict__ lb1, const int* __restrict__ lb2,
            int M0, int M1, int M2,
            int N0, int N1, int N2,
            int H0, int H1, int H2,
            double* __restrict__ objsp,    /* [3][GA]  */
            double* __restrict__ tgt)      /* [4][TGT_BLKS] lbox,clssp,clslab,objsub */ {
    __shared__ int    hkey[HASH];
    __shared__ int    hval[HASH];
    __shared__ double sm[BLK];

    const int h = blockIdx.y;
    const int tid = threadIdx.x;

    if (h < 3) {
        // ---- obj-channel softplus partial sums ----
        const float* p = (h == 0) ? p0 : ((h == 1) ? p1 : p2);
        const int M = (h == 0) ? M0 : ((h == 1) ? M1 : M2);
        double acc = 0.0;
        const int stride = gridDim.x * BLK;
        for (int i = blockIdx.x * BLK + tid; i < M; i += stride) {
            acc += (double)softplusf(p[(size_t)i * 85 + 4]);
        }
        sm[tid] = acc;
        __syncthreads();
        for (int s = BLK / 2; s > 0; s >>= 1) {
            if (tid < (unsigned)s) sm[tid] += sm[tid + s];
            __syncthreads();
        }
        if (tid == 0) objsp[h * gridDim.x + blockIdx.x] = sm[0];
        return;
    }

    // ---- per-target blocks ----
    const int nb0 = (N0 + BLK - 1) / BLK;   // 16
    const int nb1 = (N1 + BLK - 1) / BLK;   // 8
    const int nb2 = (N2 + BLK - 1) / BLK;   // 4
    const int nbt = nb0 + nb1 + nb2;        // 28
    const int bx = blockIdx.x;
    if (bx >= nbt) return;

    int head, blk;
    if (bx < nb0)            { head = 0; blk = bx; }
    else if (bx < nb0 + nb1) { head = 1; blk = bx - nb0; }
    else                     { head = 2; blk = bx - nb0 - nb1; }

    const float* pi  = (head == 0) ? p0  : ((head == 1) ? p1  : p2);
    const int*   idx = (head == 0) ? i0  : ((head == 1) ? i1  : i2);
    const float* tbx = (head == 0) ? tb0 : ((head == 1) ? tb1 : tb2);
    const float* anc = (head == 0) ? an0 : ((head == 1) ? an1 : an2);
    const int*   lab = (head == 0) ? lb0 : ((head == 1) ? lb1 : lb2);
    const int N = (head == 0) ? N0 : ((head == 1) ? N1 : N2);
    const int H = (head == 0) ? H0 : ((head == 1) ? H1 : H2);

    // build the head's full last-wins table in LDS
    for (int i = tid; i < HASH; i += BLK) { hkey[i] = -1; hval[i] = -1; }
    __syncthreads();
    for (int t = tid; t < N; t += BLK) {
        const int cell = cell_of(idx, N, H, t);
        const int slot = hash_insert(hkey, cell);
        atomicMax(&hval[slot], t);
    }
    __syncthreads();

    const int n = blk * BLK + tid;
    double lbox = 0.0, clssp = 0.0, clslab = 0.0, objsub = 0.0;

    if (n < N) {
        const int c = cell_of(idx, N, H, n);
        const size_t base = (size_t)c * 85;

        const float lx = pi[base + 0], ly = pi[base + 1];
        const float lw = pi[base + 2], lh = pi[base + 3];
        const float xo = pi[base + 4];

        const float px = sigmoidf_(lx) * 2.0f - 0.5f;
        const float py = sigmoidf_(ly) * 2.0f - 0.5f;
        const float sw = sigmoidf_(lw) * 2.0f;
        const float sh = sigmoidf_(lh) * 2.0f;
        const float pw = sw * sw * anc[(size_t)n * 2 + 0];
        const float ph = sh * sh * anc[(size_t)n * 2 + 1];

        const float tx = tbx[(size_t)n * 4 + 0], ty = tbx[(size_t)n * 4 + 1];
        const float tw = tbx[(size_t)n * 4 + 2], th = tbx[(size_t)n * 4 + 3];

        // CIoU (box1 = pred, box2 = target)
        const float b1x1 = px - pw * 0.5f, b1x2 = px + pw * 0.5f;
        const float b1y1 = py - ph * 0.5f, b1y2 = py + ph * 0.5f;
        const float b2x1 = tx - tw * 0.5f, b2x2 = tx + tw * 0.5f;
        const float b2y1 = ty - th * 0.5f, b2y2 = ty + th * 0.5f;

        const float iw = fmaxf(fminf(b1x2, b2x2) - fmaxf(b1x1, b2x1), 0.0f);
        const float ih = fmaxf(fminf(b1y2, b2y2) - fmaxf(b1y1, b2y1), 0.0f);
        const float inter = iw * ih;
        const float uni = pw * ph + tw * th - inter + 1e-7f;
        const float iou = inter / uni;

        const float cw = fmaxf(b1x2, b2x2) - fminf(b1x1, b2x1);
        const float chh = fmaxf(b1y2, b2y2) - fminf(b1y1, b2y1);
        const float c2 = cw * cw + chh * chh + 1e-7f;
        const float dx = b2x1 + b2x2 - b1x1 - b1x2;
        const float dy = b2y1 + b2y2 - b1y1 - b1y2;
        const float rho2 = (dx * dx + dy * dy) * 0.25f;
        const float dat = atanf(tw / (th + 1e-7f)) - atanf(pw / (ph + 1e-7f));
        const float v = 0.4052847345693511f * dat * dat;   // 4/pi^2
        const float alpha = v / (v - iou + (1.0f + 1e-7f));
        const float ciou = iou - (rho2 / c2 + v * alpha);

        lbox = 1.0 - (double)ciou;

        double sp = 0.0;
        for (int cc = 0; cc < 80; ++cc) sp += (double)softplusf(pi[base + 5 + cc]);
        clssp = sp;
        clslab = (double)pi[base + 5 + lab[n]];

        if (hval[hash_lookup(hkey, c)] == n) {          // last duplicate wins
            objsub = (double)fmaxf(ciou, 0.0f) * (double)xo;
        }
    }

    __syncthreads();   // hash reads done; sm reuse below is fine (separate buf)
    double vals[4] = {lbox, clssp, clslab, objsub};
    for (int k = 0; k < 4; ++k) {
        sm[tid] = vals[k];
        __syncthreads();
        for (int s = BLK / 2; s > 0; s >>= 1) {
            if (tid < (unsigned)s) sm[tid] += sm[tid + s];
            __syncthreads();
        }
        if (tid == 0) tgt[k * nbt + bx] = sm[0];
        __syncthreads();
    }
}

// ---------------- Kernel 2: final combine ------------------------------------
__global__ void __launch_bounds__(BLK)
final_kernel(const double* __restrict__ objsp, int ga,
             const double* __restrict__ tgt,
             int M0, int M1, int M2,
             int N0, int N1, int N2,
             float* __restrict__ out) {
    __shared__ double sm[BLK];
    const int tid = threadIdx.x;

    // per-head obj softplus sums (parallel, fixed-order tree => deterministic)
    __shared__ double sph[3];
    for (int h = 0; h < 3; ++h) {
        double a = 0.0;
        for (int i = tid; i < ga; i += BLK) a += objsp[h * ga + i];
        sm[tid] = a;
        __syncthreads();
        for (int s = BLK / 2; s > 0; s >>= 1) {
            if (tid < (unsigned)s) sm[tid] += sm[tid + s];
            __syncthreads();
        }
        if (tid == 0) sph[h] = sm[0];
        __syncthreads();
    }

    if (tid != 0) return;

    const int nb0 = (N0 + BLK - 1) / BLK, nb1 = (N1 + BLK - 1) / BLK, nb2 = (N2 + BLK - 1) / BLK;
    const int nbt = nb0 + nb1 + nb2;
    const int beg[3] = {0, nb0, nb0 + nb1};
    const int cnt[3] = {nb0, nb1, nb2};
    const double Ms[3] = {(double)M0, (double)M1, (double)M2};
    const double Ns[3] = {(double)N0, (double)N1, (double)N2};
    const double bal[3] = {4.0, 1.0, 0.4};

    double lbox = 0.0, lobj = 0.0, lcls = 0.0;
    for (int h = 0; h < 3; ++h) {
        double lb = 0.0, cs = 0.0, cl = 0.0, os = 0.0;
        for (int i = 0; i < cnt[h]; ++i) {
            lb += tgt[0 * nbt + beg[h] + i];
            cs += tgt[1 * nbt + beg[h] + i];
            cl += tgt[2 * nbt + beg[h] + i];
            os += tgt[3 * nbt + beg[h] + i];
        }
        lbox += lb / Ns[h];
        lobj += bal[h] * (sph[h] - os) / Ms[h];
        lcls += (cs - cl) / (Ns[h] * 80.0);
    }
    lbox *= 0.05;   // _BOX_W
    lcls *= 0.5;    // _CLS_W
    const double loss = lbox + lobj + lcls;
    out[0] = (float)(loss * 16.0);  // bs = 16
    out[1] = (float)lbox;
    out[2] = (float)lobj;
    out[3] = (float)lcls;
    out[4] = (float)loss;
}

extern "C" void kernel_launch(void* const* d_in, const int* in_sizes, int n_in,
                              void* d_out, int out_size, void* d_ws, size_t ws_size,
                              hipStream_t stream) {
    const int H0 = 80, H1 = 40, H2 = 20;
    const int M0 = 16 * 3 * H0 * H0;  // 307200
    const int M1 = 16 * 3 * H1 * H1;  // 76800
    const int M2 = 16 * 3 * H2 * H2;  // 19200

    // Input index mapping: setup_inputs() dict order vs signature order.
    int ip[3], ii[3], it[3], ia[3], il[3];
    if (in_sizes[1] < 100000) {
        for (int h = 0; h < 3; ++h) {
            ip[h] = 5 * h; ii[h] = 5 * h + 1; it[h] = 5 * h + 2;
            ia[h] = 5 * h + 3; il[h] = 5 * h + 4;
        }
    } else {
        for (int h = 0; h < 3; ++h) {
            ip[h] = h; ii[h] = 3 + h; it[h] = 6 + h;
            ia[h] = 9 + h; il[h] = 12 + h;
        }
    }
    const float* p0 = (const float*)d_in[ip[0]];
    const float* p1 = (const float*)d_in[ip[1]];
    const float* p2 = (const float*)d_in[ip[2]];
    const int* i0 = (const int*)d_in[ii[0]];
    const int* i1 = (const int*)d_in[ii[1]];
    const int* i2 = (const int*)d_in[ii[2]];
    const float* tb0 = (const float*)d_in[it[0]];
    const float* tb1 = (const float*)d_in[it[1]];
    const float* tb2 = (const float*)d_in[it[2]];
    const float* an0 = (const float*)d_in[ia[0]];
    const float* an1 = (const float*)d_in[ia[1]];
    const float* an2 = (const float*)d_in[ia[2]];
    const int* lb0 = (const int*)d_in[il[0]];
    const int* lb1 = (const int*)d_in[il[1]];
    const int* lb2 = (const int*)d_in[il[2]];

    const int N0 = in_sizes[ii[0]] / 4;  // 4000
    const int N1 = in_sizes[ii[1]] / 4;  // 2000
    const int N2 = in_sizes[ii[2]] / 4;  // 1000

    double* objsp = (double*)d_ws;            // 3*GA
    double* tgt   = objsp + 3 * GA;           // 4*28

    main_kernel<<<dim3(GA, 4), BLK, 0, stream>>>(
        p0, p1, p2, i0, i1, i2, tb0, tb1, tb2, an0, an1, an2, lb0, lb1, lb2,
        M0, M1, M2, N0, N1, N2, H0, H1, H2, objsp, tgt);

    final_kernel<<<1, BLK, 0, stream>>>(objsp, GA, tgt, M0, M1, M2, N0, N1, N2,
                                        (float*)d_out);
}

// Round 5
// 45.221 us; speedup vs baseline: 2.0601x; 1.7608x over previous
//
#include <hip/hip_runtime.h>
#include <math.h>

// SetCriterion (YOLOv5 loss) on MI355X.
// Heads: H = {80,40,20}, N = {4000,2000,1000}, M = 16*3*H*H, rows of 85 f32.
// Output: [loss*16, lbox, lobj, lcls, loss] (float32, 5 elems).
//
// BCE identity: mean(t*sp(-x)+(1-t)*sp(x)) = mean(sp(x)) - mean(t*x).
//
// R4: wave-per-target coalesced row reads (2 loads/row), <=2 softplus/lane,
// shfl_xor reduce; 438 target blocks. Winner = global array (scatter-clear
// fused into K1, atomicMax in K2). 4 launches.
// R5 fix: final_kernel parked per-(k,h) sums inside the reduce scratch `sm`,
// which later reduce passes clobbered -> wrong loss. Park in dedicated sums[].

#define BLK 256

__device__ inline float softplusf(float x) {
    return fmaxf(x, 0.0f) + log1pf(expf(-fabsf(x)));   // logaddexp(x,0)
}
__device__ inline float sigmoidf_(float x) {
    return 1.0f / (1.0f + expf(-x));
}

// flat target t in [0, N0+N1+N2) -> head h, local n
__device__ inline void flat_target(int t, int N0, int N1, int /*N2*/,
                                   int& h, int& n) {
    if (t < N0)            { h = 0; n = t; }
    else if (t < N0 + N1)  { h = 1; n = t - N0; }
    else                   { h = 2; n = t - N0 - N1; }
}

__device__ inline int cell_of(const int* __restrict__ idx, int N, int H, int n) {
    const int b = idx[n], a = idx[N + n], gj = idx[2 * N + n], gi = idx[3 * N + n];
    return ((b * 3 + a) * H + gj) * H + gi;
}

// ---- K1: obj-channel softplus partials (4 elems/thread) + winner clear ------
__global__ void __launch_bounds__(BLK)
obj_clear_kernel(const float* __restrict__ p0, const float* __restrict__ p1,
                 const float* __restrict__ p2,
                 const int* __restrict__ i0, const int* __restrict__ i1,
                 const int* __restrict__ i2,
                 int M0, int M1, int M2,
                 int N0, int N1, int N2,
                 int H0, int H1, int H2,
                 int nObjBlocks,
                 int* __restrict__ winner,
                 double* __restrict__ objsp /* [3][nObjBlocks] */) {
    const int tid = threadIdx.x;
    const int bx = blockIdx.x;

    if (bx >= nObjBlocks) {
        // scatter-clear winner cells (winner only read at touched cells)
        const int t = (bx - nObjBlocks) * BLK + tid;
        const int Ntot = N0 + N1 + N2;
        if (t >= Ntot) return;
        int h, n; flat_target(t, N0, N1, N2, h, n);
        const int* idx = (h == 0) ? i0 : ((h == 1) ? i1 : i2);
        const int  N   = (h == 0) ? N0 : ((h == 1) ? N1 : N2);
        const int  H   = (h == 0) ? H0 : ((h == 1) ? H1 : H2);
        const int  off = (h == 0) ? 0  : ((h == 1) ? M0 : M0 + M1);
        winner[off + cell_of(idx, N, H, n)] = -1;
        return;
    }

    const int T = nObjBlocks * BLK;
    const int Mtot = M0 + M1 + M2;
    double a0 = 0.0, a1 = 0.0, a2 = 0.0;
#pragma unroll
    for (int k = 0; k < 4; ++k) {
        const int e = bx * BLK + tid + k * T;
        if (e < M0)            a0 += (double)softplusf(p0[(size_t)e * 85 + 4]);
        else if (e < M0 + M1)  a1 += (double)softplusf(p1[(size_t)(e - M0) * 85 + 4]);
        else if (e < Mtot)     a2 += (double)softplusf(p2[(size_t)(e - M0 - M1) * 85 + 4]);
    }

    __shared__ double sm[BLK];
    double vals[3] = {a0, a1, a2};
    for (int h = 0; h < 3; ++h) {
        sm[tid] = vals[h];
        __syncthreads();
        for (int s = BLK / 2; s > 0; s >>= 1) {
            if (tid < (unsigned)s) sm[tid] += sm[tid + s];
            __syncthreads();
        }
        if (tid == 0) objsp[h * nObjBlocks + bx] = sm[0];
        __syncthreads();
    }
}

// ---- K2: last-duplicate-wins via atomicMax ----------------------------------
__global__ void __launch_bounds__(BLK)
winner_kernel(const int* __restrict__ i0, const int* __restrict__ i1,
              const int* __restrict__ i2,
              int M0, int M1,
              int N0, int N1, int N2,
              int H0, int H1, int H2,
              int* __restrict__ winner) {
    const int t = blockIdx.x * BLK + threadIdx.x;
    const int Ntot = N0 + N1 + N2;
    if (t >= Ntot) return;
    int h, n; flat_target(t, N0, N1, N2, h, n);
    const int* idx = (h == 0) ? i0 : ((h == 1) ? i1 : i2);
    const int  N   = (h == 0) ? N0 : ((h == 1) ? N1 : N2);
    const int  H   = (h == 0) ? H0 : ((h == 1) ? H1 : H2);
    const int  off = (h == 0) ? 0  : ((h == 1) ? M0 : M0 + M1);
    atomicMax(&winner[off + cell_of(idx, N, H, n)], n);
}

// ---- K3: per-target work, wave-per-target coalesced row reads ---------------
#define TPB 16           // targets per block
#define TPW 4            // targets per wave (4 waves/block)

__global__ void __launch_bounds__(BLK)
target_kernel(const float* __restrict__ p0, const float* __restrict__ p1, const float* __restrict__ p2,
              const int* __restrict__ i0, const int* __restrict__ i1, const int* __restrict__ i2,
              const float* __restrict__ tb0, const float* __restrict__ tb1, const float* __restrict__ tb2,
              const float* __restrict__ an0, const float* __restrict__ an1, const float* __restrict__ an2,
              const int* __restrict__ lb0, const int* __restrict__ lb1, const int* __restrict__ lb2,
              int M0, int M1,
              int N0, int N1, int N2,
              int H0, int H1, int H2,
              const int* __restrict__ winner,
              double* __restrict__ tgt /* [4][gridDim.x] */) {
    __shared__ int   s_cell[TPB];
    __shared__ int   s_lab[TPB];
    __shared__ float s_lx[TPB], s_ly[TPB], s_lw[TPB], s_lh[TPB], s_xo[TPB];
    __shared__ float s_sp[TPB], s_labv[TPB];
    __shared__ double sm[BLK];

    const int tid  = threadIdx.x;
    const int lane = tid & 63;
    const int w    = tid >> 6;
    const int g0   = blockIdx.x * TPB;
    const int Ntot = N0 + N1 + N2;

    // phase 0: cells + labels for the block's targets (parallel, scattered)
    if (tid < TPB) {
        const int g = g0 + tid;
        if (g < Ntot) {
            int h, n; flat_target(g, N0, N1, N2, h, n);
            const int* idx = (h == 0) ? i0 : ((h == 1) ? i1 : i2);
            const int* lab = (h == 0) ? lb0 : ((h == 1) ? lb1 : lb2);
            const int  N   = (h == 0) ? N0 : ((h == 1) ? N1 : N2);
            const int  H   = (h == 0) ? H0 : ((h == 1) ? H1 : H2);
            s_cell[tid] = cell_of(idx, N, H, n);
            s_lab[tid]  = lab[n];
        }
    }
    __syncthreads();

    // phase 1: wave-per-target coalesced row read + softplus reduce
    for (int i = 0; i < TPW; ++i) {
        const int j = w * TPW + i;
        const int g = g0 + j;
        if (g >= Ntot) break;
        int h, n; flat_target(g, N0, N1, N2, h, n);
        const float* pi = (h == 0) ? p0 : ((h == 1) ? p1 : p2);
        const size_t base = (size_t)s_cell[j] * 85;

        const float v0 = pi[base + lane];                            // 0..63
        const float v1 = (lane < 21) ? pi[base + 64 + lane] : 0.0f;  // 64..84

        float sp = 0.0f;
        if (lane >= 5) sp = softplusf(v0);        // classes 0..58
        if (lane < 21) sp += softplusf(v1);       // classes 59..79
        for (int m = 32; m > 0; m >>= 1) sp += __shfl_xor(sp, m);

        const int p = 5 + s_lab[j];
        const float labv = (p < 64) ? __shfl(v0, p) : __shfl(v1, p - 64);

        const float lx = __shfl(v0, 0), ly = __shfl(v0, 1);
        const float lw = __shfl(v0, 2), lh = __shfl(v0, 3);
        const float xo = __shfl(v0, 4);

        if (lane == 0) {
            s_lx[j] = lx; s_ly[j] = ly; s_lw[j] = lw; s_lh[j] = lh;
            s_xo[j] = xo; s_sp[j] = sp; s_labv[j] = labv;
        }
    }
    __syncthreads();

    // phase 2: thread-per-target CIoU + partials
    double lbox = 0.0, clssp = 0.0, clslab = 0.0, objsub = 0.0;
    if (tid < TPB) {
        const int g = g0 + tid;
        if (g < Ntot) {
            int h, n; flat_target(g, N0, N1, N2, h, n);
            const float* tbx = (h == 0) ? tb0 : ((h == 1) ? tb1 : tb2);
            const float* anc = (h == 0) ? an0 : ((h == 1) ? an1 : an2);
            const int    off = (h == 0) ? 0  : ((h == 1) ? M0 : M0 + M1);

            const float px = sigmoidf_(s_lx[tid]) * 2.0f - 0.5f;
            const float py = sigmoidf_(s_ly[tid]) * 2.0f - 0.5f;
            const float sw = sigmoidf_(s_lw[tid]) * 2.0f;
            const float sh = sigmoidf_(s_lh[tid]) * 2.0f;
            const float pw = sw * sw * anc[(size_t)n * 2 + 0];
            const float ph = sh * sh * anc[(size_t)n * 2 + 1];

            const float tx = tbx[(size_t)n * 4 + 0], ty = tbx[(size_t)n * 4 + 1];
            const float tw = tbx[(size_t)n * 4 + 2], th = tbx[(size_t)n * 4 + 3];

            const float b1x1 = px - pw * 0.5f, b1x2 = px + pw * 0.5f;
            const float b1y1 = py - ph * 0.5f, b1y2 = py + ph * 0.5f;
            const float b2x1 = tx - tw * 0.5f, b2x2 = tx + tw * 0.5f;
            const float b2y1 = ty - th * 0.5f, b2y2 = ty + th * 0.5f;

            const float iw = fmaxf(fminf(b1x2, b2x2) - fmaxf(b1x1, b2x1), 0.0f);
            const float ih = fmaxf(fminf(b1y2, b2y2) - fmaxf(b1y1, b2y1), 0.0f);
            const float inter = iw * ih;
            const float uni = pw * ph + tw * th - inter + 1e-7f;
            const float iou = inter / uni;

            const float cw  = fmaxf(b1x2, b2x2) - fminf(b1x1, b2x1);
            const float chh = fmaxf(b1y2, b2y2) - fminf(b1y1, b2y1);
            const float c2 = cw * cw + chh * chh + 1e-7f;
            const float dx = b2x1 + b2x2 - b1x1 - b1x2;
            const float dy = b2y1 + b2y2 - b1y1 - b1y2;
            const float rho2 = (dx * dx + dy * dy) * 0.25f;
            const float dat = atanf(tw / (th + 1e-7f)) - atanf(pw / (ph + 1e-7f));
            const float v = 0.4052847345693511f * dat * dat;   // 4/pi^2
            const float alpha = v / (v - iou + (1.0f + 1e-7f));
            const float ciou = iou - (rho2 / c2 + v * alpha);

            lbox  = 1.0 - (double)ciou;
            clssp = (double)s_sp[tid];
            clslab = (double)s_labv[tid];
            if (winner[off + s_cell[tid]] == n) {   // last duplicate wins
                objsub = (double)fmaxf(ciou, 0.0f) * (double)s_xo[tid];
            }
        }
    }

    double vals[4] = {lbox, clssp, clslab, objsub};
    for (int k = 0; k < 4; ++k) {
        sm[tid] = vals[k];
        __syncthreads();
        for (int s = BLK / 2; s > 0; s >>= 1) {
            if (tid < (unsigned)s) sm[tid] += sm[tid + s];
            __syncthreads();
        }
        if (tid == 0) tgt[k * gridDim.x + blockIdx.x] = sm[0];
        __syncthreads();
    }
}

// ---- K4: final combine ------------------------------------------------------
__global__ void __launch_bounds__(BLK)
final_kernel(const double* __restrict__ objsp, int nObjBlocks,
             const double* __restrict__ tgt, int nTgtBlocks,
             int M0, int M1, int M2,
             int N0, int N1, int N2,
             float* __restrict__ out) {
    __shared__ double sm[BLK];
    __shared__ double sums[15];   // [0..2]=obj sp per head; [3+k*3+h]=tgt sums
    const int tid = threadIdx.x;

    for (int h = 0; h < 3; ++h) {
        double a = 0.0;
        for (int i = tid; i < nObjBlocks; i += BLK) a += objsp[h * nObjBlocks + i];
        sm[tid] = a;
        __syncthreads();
        for (int s = BLK / 2; s > 0; s >>= 1) {
            if (tid < (unsigned)s) sm[tid] += sm[tid + s];
            __syncthreads();
        }
        if (tid == 0) sums[h] = sm[0];
        __syncthreads();
    }

    // head boundaries are block-aligned: N0=4000, N0+N1=6000 both /16 exact.
    const int nb0  = (N0 + TPB - 1) / TPB;             // 250
    const int nb01 = (N0 + N1 + TPB - 1) / TPB;        // 375
    for (int k = 0; k < 4; ++k) {
        for (int h = 0; h < 3; ++h) {
            const int lo = (h == 0) ? 0 : ((h == 1) ? nb0 : nb01);
            const int hi = (h == 0) ? nb0 : ((h == 1) ? nb01 : nTgtBlocks);
            double a = 0.0;
            for (int i = lo + tid; i < hi; i += BLK) a += tgt[k * nTgtBlocks + i];
            sm[tid] = a;
            __syncthreads();
            for (int s = BLK / 2; s > 0; s >>= 1) {
                if (tid < (unsigned)s) sm[tid] += sm[tid + s];
                __syncthreads();
            }
            if (tid == 0) sums[3 + k * 3 + h] = sm[0];
            __syncthreads();
        }
    }

    if (tid != 0) return;
    const double Ms[3] = {(double)M0, (double)M1, (double)M2};
    const double Ns[3] = {(double)N0, (double)N1, (double)N2};
    const double bal[3] = {4.0, 1.0, 0.4};
    double lbox = 0.0, lobj = 0.0, lcls = 0.0;
    for (int h = 0; h < 3; ++h) {
        const double lb = sums[3 + 0 * 3 + h];
        const double cs = sums[3 + 1 * 3 + h];
        const double cl = sums[3 + 2 * 3 + h];
        const double os = sums[3 + 3 * 3 + h];
        lbox += lb / Ns[h];
        lobj += bal[h] * (sums[h] - os) / Ms[h];
        lcls += (cs - cl) / (Ns[h] * 80.0);
    }
    lbox *= 0.05;   // _BOX_W
    lcls *= 0.5;    // _CLS_W
    const double loss = lbox + lobj + lcls;
    out[0] = (float)(loss * 16.0);  // bs = 16
    out[1] = (float)lbox;
    out[2] = (float)lobj;
    out[3] = (float)lcls;
    out[4] = (float)loss;
}

extern "C" void kernel_launch(void* const* d_in, const int* in_sizes, int n_in,
                              void* d_out, int out_size, void* d_ws, size_t ws_size,
                              hipStream_t stream) {
    const int H0 = 80, H1 = 40, H2 = 20;
    const int M0 = 16 * 3 * H0 * H0;  // 307200
    const int M1 = 16 * 3 * H1 * H1;  // 76800
    const int M2 = 16 * 3 * H2 * H2;  // 19200

    int ip[3], ii[3], it[3], ia[3], il[3];
    if (in_sizes[1] < 100000) {
        for (int h = 0; h < 3; ++h) {
            ip[h] = 5 * h; ii[h] = 5 * h + 1; it[h] = 5 * h + 2;
            ia[h] = 5 * h + 3; il[h] = 5 * h + 4;
        }
    } else {
        for (int h = 0; h < 3; ++h) {
            ip[h] = h; ii[h] = 3 + h; it[h] = 6 + h;
            ia[h] = 9 + h; il[h] = 12 + h;
        }
    }
    const float* p0 = (const float*)d_in[ip[0]];
    const float* p1 = (const float*)d_in[ip[1]];
    const float* p2 = (const float*)d_in[ip[2]];
    const int* i0 = (const int*)d_in[ii[0]];
    const int* i1 = (const int*)d_in[ii[1]];
    const int* i2 = (const int*)d_in[ii[2]];
    const float* tb0 = (const float*)d_in[it[0]];
    const float* tb1 = (const float*)d_in[it[1]];
    const float* tb2 = (const float*)d_in[it[2]];
    const float* an0 = (const float*)d_in[ia[0]];
    const float* an1 = (const float*)d_in[ia[1]];
    const float* an2 = (const float*)d_in[ia[2]];
    const int* lb0 = (const int*)d_in[il[0]];
    const int* lb1 = (const int*)d_in[il[1]];
    const int* lb2 = (const int*)d_in[il[2]];

    const int N0 = in_sizes[ii[0]] / 4;  // 4000
    const int N1 = in_sizes[ii[1]] / 4;  // 2000
    const int N2 = in_sizes[ii[2]] / 4;  // 1000
    const int Ntot = N0 + N1 + N2;       // 7000
    const int Mtot = M0 + M1 + M2;       // 403200

    // grids
    const int nObjBlocks = ((Mtot + 3) / 4 + BLK - 1) / BLK;       // 394
    const int nClrBlocks = (Ntot + BLK - 1) / BLK;                 // 28
    const int nTgtBlocks = (Ntot + TPB - 1) / TPB;                 // 438

    // workspace
    int* winner = (int*)d_ws;                                      // Mtot ints
    char* dptr = (char*)d_ws + (((size_t)Mtot * 4 + 255) / 256) * 256;
    double* objsp = (double*)dptr;                                 // 3*nObjBlocks
    double* tgt   = objsp + 3 * nObjBlocks;                        // 4*nTgtBlocks

    obj_clear_kernel<<<nObjBlocks + nClrBlocks, BLK, 0, stream>>>(
        p0, p1, p2, i0, i1, i2, M0, M1, M2, N0, N1, N2, H0, H1, H2,
        nObjBlocks, winner, objsp);

    winner_kernel<<<nClrBlocks, BLK, 0, stream>>>(
        i0, i1, i2, M0, M1, N0, N1, N2, H0, H1, H2, winner);

    target_kernel<<<nTgtBlocks, BLK, 0, stream>>>(
        p0, p1, p2, i0, i1, i2, tb0, tb1, tb2, an0, an1, an2, lb0, lb1, lb2,
        M0, M1, N0, N1, N2, H0, H1, H2, winner, tgt);

    final_kernel<<<1, BLK, 0, stream>>>(objsp, nObjBlocks, tgt, nTgtBlocks,
                                        M0, M1, M2, N0, N1, N2, (float*)d_out);
}